// Round 1
// baseline (214.459 us; speedup 1.0000x reference)
//
#include <hip/hip_runtime.h>
#include <hip/hip_bf16.h>

#define RANK 16
#define A1d 64
#define A2d 8
#define B1d 64
#define B2d 8
#define BATCH 32768
#define K_DIM 4096   // A1*B1
#define N_DIM 64     // A2*B2

typedef __bf16 bf16x8 __attribute__((ext_vector_type(8)));
typedef float floatx4 __attribute__((ext_vector_type(4)));
typedef unsigned short ushort8 __attribute__((ext_vector_type(8)));

__device__ inline unsigned short f2bf(float f) {
  unsigned u = __builtin_bit_cast(unsigned, f);
  u += 0x7fffu + ((u >> 16) & 1u);   // round-to-nearest-even
  return (unsigned short)(u >> 16);
}

// wT[n][k] = w[k][n] = sum_r s[i][j]*a[r][i][j]*b[r][kk][l]
//   k = i*64 + kk  (i in A1, kk in B1), n = j*8 + l (j in A2, l in B2)
__global__ __launch_bounds__(256) void build_wT(
    const float* __restrict__ s, const float* __restrict__ a,
    const float* __restrict__ b, unsigned short* __restrict__ wT) {
  int idx = blockIdx.x * 256 + threadIdx.x;   // idx = n*4096 + k
  int n = idx >> 12;
  int k = idx & 4095;
  int j = n >> 3, l = n & 7;
  int i = k >> 6, kk = k & 63;
  float acc = 0.f;
  #pragma unroll
  for (int r = 0; r < RANK; ++r) {
    acc += a[r * 512 + i * 8 + j] * b[r * 512 + kk * 8 + l];
  }
  acc *= s[i * 8 + j];
  wT[idx] = f2bf(acc);
}

// out[m][n] = sum_k x[m][k]*w[k][n] + bias[n]
// Block: 256 thr = 4 waves; each wave: 16 rows x 64 cols via 4 col-fragments.
__global__ __launch_bounds__(256, 4) void kron_gemm(
    const float* __restrict__ x, const unsigned short* __restrict__ wT,
    const float* __restrict__ bias, float* __restrict__ out) {
  const int lane = threadIdx.x & 63;
  const int wave = threadIdx.x >> 6;
  const int ln15 = lane & 15;          // A row / B col / D col
  const int kseg = lane >> 4;          // 0..3
  const int m0 = blockIdx.x * 64 + wave * 16;

  const float* xrow = x + (size_t)(m0 + ln15) * K_DIM;
  const unsigned short* wbase = wT + (size_t)ln15 * K_DIM;

  floatx4 acc[4] = {};

  #pragma unroll 2
  for (int k0 = 0; k0 < K_DIM; k0 += 32) {
    const int kb = k0 + kseg * 8;
    float4 a0 = *(const float4*)(xrow + kb);
    float4 a1 = *(const float4*)(xrow + kb + 4);
    ushort8 au;
    au[0] = f2bf(a0.x); au[1] = f2bf(a0.y); au[2] = f2bf(a0.z); au[3] = f2bf(a0.w);
    au[4] = f2bf(a1.x); au[5] = f2bf(a1.y); au[6] = f2bf(a1.z); au[7] = f2bf(a1.w);
    bf16x8 af = __builtin_bit_cast(bf16x8, au);
    #pragma unroll
    for (int c = 0; c < 4; ++c) {
      bf16x8 bfrag = *(const bf16x8*)(wbase + (size_t)c * 16 * K_DIM + kb);
      acc[c] = __builtin_amdgcn_mfma_f32_16x16x32_bf16(af, bfrag, acc[c], 0, 0, 0);
    }
  }

  #pragma unroll
  for (int c = 0; c < 4; ++c) {
    const int col = c * 16 + ln15;
    const float bv = bias[col];
    float* op = out + (size_t)(m0 + kseg * 4) * N_DIM + col;
    #pragma unroll
    for (int r = 0; r < 4; ++r) {
      op[r * N_DIM] = acc[c][r] + bv;
    }
  }
}

extern "C" void kernel_launch(void* const* d_in, const int* in_sizes, int n_in,
                              void* d_out, int out_size, void* d_ws, size_t ws_size,
                              hipStream_t stream) {
  const float* x    = (const float*)d_in[0];
  const float* s    = (const float*)d_in[1];
  const float* a    = (const float*)d_in[2];
  const float* b    = (const float*)d_in[3];
  const float* bias = (const float*)d_in[4];
  float* out = (float*)d_out;
  unsigned short* wT = (unsigned short*)d_ws;   // 4096*64*2B = 512 KB

  build_wT<<<(N_DIM * K_DIM) / 256, 256, 0, stream>>>(s, a, b, wT);
  kron_gemm<<<BATCH / 64, 256, 0, stream>>>(x, wT, bias, out);
}

// Round 2
// 202.065 us; speedup vs baseline: 1.0613x; 1.0613x over previous
//
#include <hip/hip_runtime.h>
#include <hip/hip_bf16.h>

#define RANK 16
#define BATCH 32768
#define K_DIM 4096   // A1*B1
#define N_DIM 64     // A2*B2
#define LSTR 68      // LDS row stride (floats): 16B-aligned, 2-way-free banks

typedef __bf16 bf16x8 __attribute__((ext_vector_type(8)));
typedef float floatx4 __attribute__((ext_vector_type(4)));
typedef unsigned short ushort8 __attribute__((ext_vector_type(8)));

__device__ inline unsigned short f2bf(float f) {
  unsigned u = __builtin_bit_cast(unsigned, f);
  u += 0x7fffu + ((u >> 16) & 1u);   // round-to-nearest-even
  return (unsigned short)(u >> 16);
}

__device__ inline bf16x8 cvt8(float4 a0, float4 a1) {
  ushort8 au;
  au[0] = f2bf(a0.x); au[1] = f2bf(a0.y); au[2] = f2bf(a0.z); au[3] = f2bf(a0.w);
  au[4] = f2bf(a1.x); au[5] = f2bf(a1.y); au[6] = f2bf(a1.z); au[7] = f2bf(a1.w);
  return __builtin_bit_cast(bf16x8, au);
}

// wT[n][k] = w[k][n] = sum_r s[i][j]*a[r][i][j]*b[r][kk][l]
__global__ __launch_bounds__(256) void build_wT(
    const float* __restrict__ s, const float* __restrict__ a,
    const float* __restrict__ b, unsigned short* __restrict__ wT) {
  int idx = blockIdx.x * 256 + threadIdx.x;   // idx = n*4096 + k
  int n = idx >> 12;
  int k = idx & 4095;
  int j = n >> 3, l = n & 7;
  int i = k >> 6, kk = k & 63;
  float acc = 0.f;
  #pragma unroll
  for (int r = 0; r < RANK; ++r) {
    acc += a[r * 512 + i * 8 + j] * b[r * 512 + kk * 8 + l];
  }
  acc *= s[i * 8 + j];
  wT[idx] = f2bf(acc);
}

// Block = 256 thr = 4 waves = 2 row-tiles x 2 K-halves. Each wave:
// 16 rows x 64 cols x K=2048 via mfma_f32_16x16x32_bf16, 2-stage reg pipeline.
// LDS cross-K reduce + coalesced float4 epilogue.
__global__ __launch_bounds__(256, 4) void kron_gemm(
    const float* __restrict__ x, const unsigned short* __restrict__ wT,
    const float* __restrict__ bias, float* __restrict__ out) {
  __shared__ __align__(16) float red[2][32][LSTR];

  const int tid  = threadIdx.x;
  const int lane = tid & 63;
  const int wave = tid >> 6;
  const int rt   = wave & 1;     // row tile within block
  const int kh   = wave >> 1;    // K half
  const int ln15 = lane & 15;    // A row / B col / D col
  const int kseg = lane >> 4;    // 0..3

  const int m0 = blockIdx.x * 32 + rt * 16;
  const float* xp = x + (size_t)(m0 + ln15) * K_DIM + kh * 2048 + kseg * 8;
  const unsigned short* wp = wT + (size_t)ln15 * K_DIM + kh * 2048 + kseg * 8;

  floatx4 acc[4] = {};

  // ---- prologue: preload pipeline stages A (it=0) and B (it=1) ----
  float4 xa0 = *(const float4*)(xp +  0), xb0 = *(const float4*)(xp +  4);
  float4 xa1 = *(const float4*)(xp + 32), xb1 = *(const float4*)(xp + 36);
  bf16x8 w0[4], w1[4];
  #pragma unroll
  for (int c = 0; c < 4; ++c) {
    w0[c] = *(const bf16x8*)(wp + (size_t)c * 16 * K_DIM);
    w1[c] = *(const bf16x8*)(wp + (size_t)c * 16 * K_DIM + 32);
  }

  // ---- steady state: 64 K-iterations total, compute 0..61 here ----
  for (int it = 0; it < 62; it += 2) {
    // stage A: compute it, prefetch it+2
    {
      bf16x8 af = cvt8(xa0, xb0);
      const float* xn = xp + (size_t)(it + 2) * 32;
      const unsigned short* wn = wp + (size_t)(it + 2) * 32;
      xa0 = *(const float4*)(xn);
      xb0 = *(const float4*)(xn + 4);
      #pragma unroll
      for (int c = 0; c < 4; ++c) {
        acc[c] = __builtin_amdgcn_mfma_f32_16x16x32_bf16(af, w0[c], acc[c], 0, 0, 0);
        w0[c] = *(const bf16x8*)(wn + (size_t)c * 16 * K_DIM);
      }
    }
    // stage B: compute it+1, prefetch it+3
    {
      bf16x8 bf = cvt8(xa1, xb1);
      const float* xn = xp + (size_t)(it + 3) * 32;
      const unsigned short* wn = wp + (size_t)(it + 3) * 32;
      xa1 = *(const float4*)(xn);
      xb1 = *(const float4*)(xn + 4);
      #pragma unroll
      for (int c = 0; c < 4; ++c) {
        acc[c] = __builtin_amdgcn_mfma_f32_16x16x32_bf16(bf, w1[c], acc[c], 0, 0, 0);
        w1[c] = *(const bf16x8*)(wn + (size_t)c * 16 * K_DIM);
      }
    }
  }
  // ---- epilogue: compute it=62, 63 ----
  {
    bf16x8 af = cvt8(xa0, xb0);
    #pragma unroll
    for (int c = 0; c < 4; ++c)
      acc[c] = __builtin_amdgcn_mfma_f32_16x16x32_bf16(af, w0[c], acc[c], 0, 0, 0);
    bf16x8 bf = cvt8(xa1, xb1);
    #pragma unroll
    for (int c = 0; c < 4; ++c)
      acc[c] = __builtin_amdgcn_mfma_f32_16x16x32_bf16(bf, w1[c], acc[c], 0, 0, 0);
  }

  // ---- cross-K-half reduce via LDS ----
  #pragma unroll
  for (int c = 0; c < 4; ++c) {
    #pragma unroll
    for (int r = 0; r < 4; ++r) {
      red[kh][rt * 16 + kseg * 4 + r][c * 16 + ln15] = acc[c][r];
    }
  }
  __syncthreads();

  // ---- coalesced epilogue: 32 rows x 64 cols, float4 per thread x2 ----
  const size_t obase = (size_t)blockIdx.x * 32 * N_DIM;
  #pragma unroll
  for (int p = 0; p < 2; ++p) {
    int f   = tid + p * 256;     // 0..511
    int row = f >> 4;            // 0..31
    int c4  = f & 15;            // 0..15
    float4 v0 = *(const float4*)&red[0][row][c4 * 4];
    float4 v1 = *(const float4*)&red[1][row][c4 * 4];
    float4 bv = *(const float4*)&bias[c4 * 4];
    float4 o;
    o.x = v0.x + v1.x + bv.x;
    o.y = v0.y + v1.y + bv.y;
    o.z = v0.z + v1.z + bv.z;
    o.w = v0.w + v1.w + bv.w;
    *(float4*)(out + obase + (size_t)row * N_DIM + c4 * 4) = o;
  }
}

extern "C" void kernel_launch(void* const* d_in, const int* in_sizes, int n_in,
                              void* d_out, int out_size, void* d_ws, size_t ws_size,
                              hipStream_t stream) {
  const float* x    = (const float*)d_in[0];
  const float* s    = (const float*)d_in[1];
  const float* a    = (const float*)d_in[2];
  const float* b    = (const float*)d_in[3];
  const float* bias = (const float*)d_in[4];
  float* out = (float*)d_out;
  unsigned short* wT = (unsigned short*)d_ws;   // 4096*64*2B = 512 KB

  build_wT<<<(N_DIM * K_DIM) / 256, 256, 0, stream>>>(s, a, b, wT);
  kron_gemm<<<BATCH / 32, 256, 0, stream>>>(x, wT, bias, out);
}